// Round 1
// baseline (729.201 us; speedup 1.0000x reference)
//
#include <hip/hip_runtime.h>
#include <math.h>

#define NHEADS 8
#define NGROUPS 4
#define HH 24
#define WW 24
#define HW 576
#define CS 256        // channels per group
#define CHD 32        // channels per head
#define NN 2304       // HW * NGROUPS
#define TOPK 1843     // int(2304 * 0.8)
#define DIM 1024
#define EPSN 1e-12f

// ---------------------------------------------------------------------------
// Kernel 1: fused group-mix (w_qkv) + depthwise 3x3 conv (w_dw), scatter to
// head layout q/k/v[h][c][n], n = (hh*24+ww)*4 + t
// conv(sum_t wq[s,t]*x_t, wd[s]) == sum_t wq[s,t]*conv(x_t, wd[s])
// ---------------------------------------------------------------------------
__global__ __launch_bounds__(256) void qkv_conv_kernel(
    const float* __restrict__ x, const float* __restrict__ w_qkv,
    const float* __restrict__ w_dw,
    float* __restrict__ qb, float* __restrict__ kb, float* __restrict__ vb)
{
    __shared__ float xp[NGROUPS][26][26];   // zero-padded planes
    __shared__ float wq[48];
    __shared__ float wd[108];
    int c = blockIdx.x;          // 0..255 (channel within group)
    int tid = threadIdx.x;

    for (int i = tid; i < NGROUPS * 26 * 26; i += 256) ((float*)xp)[i] = 0.f;
    if (tid < 48) wq[tid] = w_qkv[tid];
    if (tid < 108) wd[tid] = w_dw[tid];
    __syncthreads();
    for (int i = tid; i < NGROUPS * HW; i += 256) {
        int t = i / HW, p = i % HW;
        int hh = p / WW, ww = p % WW;
        xp[t][hh + 1][ww + 1] = x[(size_t)(t * CS + c) * HW + p];
    }
    __syncthreads();

    int hd = c >> 5, ch = c & 31;
    for (int p = tid; p < HW; p += 256) {
        int hh = p / WW, ww = p % WW;
        float res[12];
        #pragma unroll
        for (int s = 0; s < 12; ++s) {
            float acc = 0.f;
            #pragma unroll
            for (int t = 0; t < NGROUPS; ++t) {
                float cv = 0.f;
                #pragma unroll
                for (int dh = 0; dh < 3; ++dh)
                    #pragma unroll
                    for (int dw = 0; dw < 3; ++dw)
                        cv += xp[t][hh + dh][ww + dw] * wd[s * 9 + dh * 3 + dw];
                acc += wq[s * 4 + t] * cv;
            }
            res[s] = acc;
        }
        #pragma unroll
        for (int tt = 0; tt < 4; ++tt) {
            int n = p * 4 + tt;
            size_t off = ((size_t)hd * CHD + ch) * NN + n;
            qb[off] = res[tt];
            kb[off] = res[4 + tt];
            vb[off] = res[8 + tt];
        }
    }
}

// ---------------------------------------------------------------------------
// Kernel 2: L2-normalize q and k along n per (h,c) row
// ---------------------------------------------------------------------------
__global__ __launch_bounds__(256) void normalize_kernel(float* __restrict__ qb,
                                                        float* __restrict__ kb)
{
    __shared__ float redf[8];
    int b = blockIdx.x;          // 0..511
    float* buf = (b < 256) ? qb : kb;
    int hc = b & 255;
    float* rowp = buf + (size_t)hc * NN;
    int tid = threadIdx.x;
    float ss = 0.f;
    for (int i = tid; i < NN; i += 256) { float v = rowp[i]; ss += v * v; }
    for (int off = 32; off > 0; off >>= 1) ss += __shfl_down(ss, off);
    int wid = tid >> 6, lane = tid & 63;
    if (lane == 0) redf[wid] = ss;
    __syncthreads();
    if (tid == 0) redf[4] = redf[0] + redf[1] + redf[2] + redf[3];
    __syncthreads();
    float scale = 1.f / fmaxf(sqrtf(redf[4]), EPSN);
    for (int i = tid; i < NN; i += 256) rowp[i] *= scale;
}

// ---------------------------------------------------------------------------
// Kernel 3: one block per (head, row n).  attn row -> exact radix-select of
// TOPK-th largest -> softmax over selected -> PV -> scatter to [c_full][p].
// ---------------------------------------------------------------------------
__device__ __forceinline__ unsigned fkey(float f) {
    unsigned u = __float_as_uint(f);
    return u ^ ((u >> 31) ? 0xFFFFFFFFu : 0x80000000u);  // monotonic map
}

__global__ __launch_bounds__(256) void attn_row_kernel(
    const float* __restrict__ qb, const float* __restrict__ kb,
    const float* __restrict__ vb, const float* __restrict__ temp,
    float* __restrict__ aout)
{
    __shared__ float row[NN];
    __shared__ float qv[CHD];
    __shared__ unsigned hist[256];
    __shared__ unsigned sscan[256];
    __shared__ float redf[8];
    __shared__ float red2[4][CHD];
    __shared__ unsigned bcastB, bcastAbove;
    __shared__ int cutIdx;

    int bid = blockIdx.x;
    int h = bid / NN;
    int n = bid % NN;
    int tid = threadIdx.x;
    int wid = tid >> 6, lane = tid & 63;

    const float* Kb = kb + (size_t)h * CHD * NN;
    const float* Vb = vb + (size_t)h * CHD * NN;
    if (tid < CHD) qv[tid] = qb[(size_t)h * CHD * NN + (size_t)tid * NN + n];
    __syncthreads();
    float tscale = temp[h];

    // ---- QK^T row ----
    for (int m = tid; m < NN; m += 256) {
        float d = 0.f;
        #pragma unroll
        for (int c = 0; c < CHD; ++c) d += qv[c] * Kb[c * NN + m];
        row[m] = d * tscale;
    }
    __syncthreads();

    // ---- radix select: key of TOPK-th largest ----
    unsigned prefix = 0u, pmask = 0u;
    unsigned remK = TOPK;
    unsigned lastE = 0;
    for (int shift = 24; shift >= 0; shift -= 8) {
        hist[tid] = 0;
        __syncthreads();
        for (int m = tid; m < NN; m += 256) {
            unsigned key = fkey(row[m]);
            if ((key & pmask) == prefix)
                atomicAdd(&hist[(key >> shift) & 0xFFu], 1u);
        }
        __syncthreads();
        sscan[tid] = hist[tid];
        __syncthreads();
        for (int off = 1; off < 256; off <<= 1) {
            unsigned v = (tid + off < 256) ? sscan[tid + off] : 0u;
            __syncthreads();
            sscan[tid] += v;
            __syncthreads();
        }
        unsigned nxt = (tid < 255) ? sscan[tid + 1] : 0u;
        if (sscan[tid] >= remK && nxt < remK) { bcastB = tid; bcastAbove = nxt; }
        __syncthreads();
        unsigned B = bcastB;
        remK -= bcastAbove;
        prefix |= (B << shift);
        pmask |= (0xFFu << shift);
        lastE = hist[B];
        __syncthreads();
    }
    unsigned T = prefix;

    // ---- tie handling (stable, lower-index-first like lax.top_k) ----
    if (tid == 0) cutIdx = NN - 1;
    __syncthreads();
    if (remK < lastE) {              // rare: duplicates straddle threshold
        if (tid == 0) {
            unsigned cnt = 0; int cut = NN - 1;
            for (int m = 0; m < NN; ++m) {
                if (fkey(row[m]) == T) {
                    if (++cnt == remK) { cut = m; break; }
                }
            }
            cutIdx = cut;
        }
        __syncthreads();
    }
    int cut = cutIdx;

    // ---- row max (max element is always selected) ----
    float mx = -INFINITY;
    for (int m = tid; m < NN; m += 256) mx = fmaxf(mx, row[m]);
    for (int off = 32; off > 0; off >>= 1) mx = fmaxf(mx, __shfl_down(mx, off));
    if (lane == 0) redf[wid] = mx;
    __syncthreads();
    if (tid == 0) redf[4] = fmaxf(fmaxf(redf[0], redf[1]), fmaxf(redf[2], redf[3]));
    __syncthreads();
    float rowmax = redf[4];

    // ---- exp over selected, zero elsewhere; sum ----
    float lsum = 0.f;
    for (int m = tid; m < NN; m += 256) {
        float a = row[m];
        unsigned key = fkey(a);
        bool inc = (key > T) || (key == T && m <= cut);
        float e = inc ? __expf(a - rowmax) : 0.f;
        row[m] = e;
        lsum += e;
    }
    for (int off = 32; off > 0; off >>= 1) lsum += __shfl_down(lsum, off);
    if (lane == 0) redf[wid] = lsum;
    __syncthreads();
    if (tid == 0) redf[4] = redf[0] + redf[1] + redf[2] + redf[3];
    __syncthreads();
    float rinv = 1.f / redf[4];

    // ---- PV: acc[c] = sum_m p[m] * V[c][m] ----
    float acc[CHD];
    #pragma unroll
    for (int c = 0; c < CHD; ++c) acc[c] = 0.f;
    for (int m = tid; m < NN; m += 256) {
        float pm = row[m];
        if (pm != 0.f) {
            #pragma unroll
            for (int c = 0; c < CHD; ++c) acc[c] += pm * Vb[c * NN + m];
        }
    }
    #pragma unroll
    for (int c = 0; c < CHD; ++c) {
        float v = acc[c];
        for (int off = 32; off > 0; off >>= 1) v += __shfl_down(v, off);
        if (lane == 0) red2[wid][c] = v;
    }
    __syncthreads();
    if (tid < CHD) {
        float s = (red2[0][tid] + red2[1][tid] + red2[2][tid] + red2[3][tid]) * rinv;
        int tt = n & 3, p = n >> 2;
        int cfull = tt * CS + h * CHD + tid;
        aout[(size_t)cfull * HW + p] = s;
    }
}

// ---------------------------------------------------------------------------
// Kernel 4: out = x + w_proj @ aout   (M=1024, N=576, K=1024)
// ---------------------------------------------------------------------------
#define BM 64
#define BN 64
#define BK 16
__global__ __launch_bounds__(256) void proj_kernel(
    const float* __restrict__ aout, const float* __restrict__ wproj,
    const float* __restrict__ x, float* __restrict__ out)
{
    __shared__ float As[BM][BK + 1];
    __shared__ float Bs[BK][BN + 1];
    int bx = blockIdx.x;   // p tiles: 0..8
    int by = blockIdx.y;   // o tiles: 0..15
    int tid = threadIdx.x;
    int tx = tid & 15, ty = tid >> 4;
    float acc[4][4] = {{0.f}};
    for (int kt = 0; kt < DIM; kt += BK) {
        #pragma unroll
        for (int i = 0; i < 4; ++i) {
            int idx = tid + i * 256;
            int r = idx >> 4, cc = idx & 15;
            As[r][cc] = wproj[(size_t)(by * BM + r) * DIM + kt + cc];
        }
        #pragma unroll
        for (int i = 0; i < 4; ++i) {
            int idx = tid + i * 256;
            int r = idx >> 6, p = idx & 63;
            Bs[r][p] = aout[(size_t)(kt + r) * HW + bx * BN + p];
        }
        __syncthreads();
        #pragma unroll
        for (int kk = 0; kk < BK; ++kk) {
            float a[4], b[4];
            #pragma unroll
            for (int i = 0; i < 4; ++i) a[i] = As[ty * 4 + i][kk];
            #pragma unroll
            for (int j = 0; j < 4; ++j) b[j] = Bs[kk][tx * 4 + j];
            #pragma unroll
            for (int i = 0; i < 4; ++i)
                #pragma unroll
                for (int j = 0; j < 4; ++j) acc[i][j] += a[i] * b[j];
        }
        __syncthreads();
    }
    #pragma unroll
    for (int i = 0; i < 4; ++i) {
        int o = by * BM + ty * 4 + i;
        #pragma unroll
        for (int j = 0; j < 4; ++j) {
            int p = bx * BN + tx * 4 + j;
            out[(size_t)o * HW + p] = x[(size_t)o * HW + p] + acc[i][j];
        }
    }
}

// ---------------------------------------------------------------------------
extern "C" void kernel_launch(void* const* d_in, const int* in_sizes, int n_in,
                              void* d_out, int out_size, void* d_ws, size_t ws_size,
                              hipStream_t stream)
{
    const float* x     = (const float*)d_in[0];
    const float* temp  = (const float*)d_in[1];
    const float* w_qkv = (const float*)d_in[2];
    const float* w_dw  = (const float*)d_in[3];
    const float* wproj = (const float*)d_in[4];
    float* out = (float*)d_out;

    const size_t TSZ = (size_t)NHEADS * CHD * NN;   // 589824 floats
    float* ws = (float*)d_ws;
    float* qb   = ws;
    float* kb   = ws + TSZ;
    float* vb   = ws + 2 * TSZ;
    float* aout = ws + 3 * TSZ;

    qkv_conv_kernel<<<256, 256, 0, stream>>>(x, w_qkv, w_dw, qb, kb, vb);
    normalize_kernel<<<512, 256, 0, stream>>>(qb, kb);
    attn_row_kernel<<<NHEADS * NN, 256, 0, stream>>>(qb, kb, vb, temp, aout);
    proj_kernel<<<dim3(9, 16), 256, 0, stream>>>(aout, wproj, x, out);
}

// Round 2
// 327.323 us; speedup vs baseline: 2.2278x; 2.2278x over previous
//
#include <hip/hip_runtime.h>
#include <math.h>

#define NHEADS 8
#define NGROUPS 4
#define HH 24
#define WW 24
#define HW 576
#define CS 256        // channels per group
#define CHD 32        // channels per head
#define NN 2304       // HW * NGROUPS
#define TOPK 1843     // int(2304 * 0.8)
#define DIM 1024
#define EPSN 1e-12f
#define RB 4          // rows per block in attention

// ---------------------------------------------------------------------------
// Kernel 1: fused group-mix (w_qkv) + depthwise 3x3 conv (w_dw), scatter to
// head layout q/k/v[h][c][n], n = (hh*24+ww)*4 + t
// ---------------------------------------------------------------------------
__global__ __launch_bounds__(256) void qkv_conv_kernel(
    const float* __restrict__ x, const float* __restrict__ w_qkv,
    const float* __restrict__ w_dw,
    float* __restrict__ qb, float* __restrict__ kb, float* __restrict__ vb)
{
    __shared__ float xp[NGROUPS][26][26];   // zero-padded planes
    __shared__ float wq[48];
    __shared__ float wd[108];
    int c = blockIdx.x;          // 0..255 (channel within group)
    int tid = threadIdx.x;

    for (int i = tid; i < NGROUPS * 26 * 26; i += 256) ((float*)xp)[i] = 0.f;
    if (tid < 48) wq[tid] = w_qkv[tid];
    if (tid < 108) wd[tid] = w_dw[tid];
    __syncthreads();
    for (int i = tid; i < NGROUPS * HW; i += 256) {
        int t = i / HW, p = i % HW;
        int hh = p / WW, ww = p % WW;
        xp[t][hh + 1][ww + 1] = x[(size_t)(t * CS + c) * HW + p];
    }
    __syncthreads();

    int hd = c >> 5, ch = c & 31;
    for (int p = tid; p < HW; p += 256) {
        int hh = p / WW, ww = p % WW;
        float res[12];
        #pragma unroll
        for (int s = 0; s < 12; ++s) {
            float acc = 0.f;
            #pragma unroll
            for (int t = 0; t < NGROUPS; ++t) {
                float cv = 0.f;
                #pragma unroll
                for (int dh = 0; dh < 3; ++dh)
                    #pragma unroll
                    for (int dw = 0; dw < 3; ++dw)
                        cv += xp[t][hh + dh][ww + dw] * wd[s * 9 + dh * 3 + dw];
                acc += wq[s * 4 + t] * cv;
            }
            res[s] = acc;
        }
        #pragma unroll
        for (int tt = 0; tt < 4; ++tt) {
            int n = p * 4 + tt;
            size_t off = ((size_t)hd * CHD + ch) * NN + n;
            qb[off] = res[tt];
            kb[off] = res[4 + tt];
            vb[off] = res[8 + tt];
        }
    }
}

// ---------------------------------------------------------------------------
// Kernel 2: L2-normalize q and k along n per (h,c) row
// ---------------------------------------------------------------------------
__global__ __launch_bounds__(256) void normalize_kernel(float* __restrict__ qb,
                                                        float* __restrict__ kb)
{
    __shared__ float redf[8];
    int b = blockIdx.x;          // 0..511
    float* buf = (b < 256) ? qb : kb;
    int hc = b & 255;
    float* rowp = buf + (size_t)hc * NN;
    int tid = threadIdx.x;
    float ss = 0.f;
    for (int i = tid; i < NN; i += 256) { float v = rowp[i]; ss += v * v; }
    for (int off = 32; off > 0; off >>= 1) ss += __shfl_down(ss, off);
    int wid = tid >> 6, lane = tid & 63;
    if (lane == 0) redf[wid] = ss;
    __syncthreads();
    if (tid == 0) redf[4] = redf[0] + redf[1] + redf[2] + redf[3];
    __syncthreads();
    float scale = 1.f / fmaxf(sqrtf(redf[4]), EPSN);
    for (int i = tid; i < NN; i += 256) rowp[i] *= scale;
}

// ---------------------------------------------------------------------------
// Kernel 3: one block per (head, 4 rows).  QK^T (4 rows) -> exact histogram
// select of TOPK-th largest per row -> softmax over selected -> PV with V
// loads shared across the 4 rows -> scatter to [c_full][p].
// ---------------------------------------------------------------------------
__device__ __forceinline__ unsigned fkey(float f) {
    unsigned u = __float_as_uint(f);
    return u ^ ((u >> 31) ? 0xFFFFFFFFu : 0x80000000u);  // monotonic map
}
__device__ __forceinline__ float fkey_inv(unsigned k) {
    return __uint_as_float((k & 0x80000000u) ? (k ^ 0x80000000u) : ~k);
}

__global__ __launch_bounds__(256) void attn_rows_kernel(
    const float* __restrict__ qb, const float* __restrict__ kb,
    const float* __restrict__ vb, const float* __restrict__ temp,
    float* __restrict__ aout)
{
    __shared__ float rows[RB][NN];          // 36864 B
    __shared__ float qv[RB][CHD];
    __shared__ unsigned hist[256];
    __shared__ unsigned candk[64];
    __shared__ unsigned wtot[4];
    __shared__ unsigned mred[4][RB][2];     // per-wave min/max
    __shared__ float fred[4][RB];
    __shared__ unsigned rowKmin[RB], rowKmax[RB];
    __shared__ unsigned sBin, sAbove, sCnt, sScnt, sT, sTie, sEq;
    __shared__ unsigned Tkey[RB];
    __shared__ int cutIdx[RB];
    __shared__ float rdenom[RB];

    int bid = blockIdx.x;
    int h = bid / HW;            // 0..7
    int g = bid % HW;            // 0..575 (spatial position p; rows n = g*4+r)
    int tid = threadIdx.x;
    int lane = tid & 63, wid = tid >> 6;

    const float* Qh = qb + (size_t)h * CHD * NN;
    const float* Kb = kb + (size_t)h * CHD * NN;
    const float* Vb = vb + (size_t)h * CHD * NN;
    float tscale = temp[h];

    if (tid < RB * CHD) {
        int r = tid >> 5, c = tid & 31;
        qv[r][c] = Qh[(size_t)c * NN + g * RB + r];
    }
    __syncthreads();

    // ---- QK^T for 4 rows (each thread owns 9 columns m) ----
    {
        float d[RB][9];
        #pragma unroll
        for (int r = 0; r < RB; ++r)
            #pragma unroll
            for (int j = 0; j < 9; ++j) d[r][j] = 0.f;
        for (int c = 0; c < CHD; ++c) {
            float q0 = qv[0][c], q1 = qv[1][c], q2 = qv[2][c], q3 = qv[3][c];
            const float* kp = Kb + (size_t)c * NN + tid;
            #pragma unroll
            for (int j = 0; j < 9; ++j) {
                float kcm = kp[j * 256];
                d[0][j] += q0 * kcm; d[1][j] += q1 * kcm;
                d[2][j] += q2 * kcm; d[3][j] += q3 * kcm;
            }
        }
        #pragma unroll
        for (int j = 0; j < 9; ++j) {
            int m = tid + j * 256;
            rows[0][m] = d[0][j] * tscale;
            rows[1][m] = d[1][j] * tscale;
            rows[2][m] = d[2][j] * tscale;
            rows[3][m] = d[3][j] * tscale;
        }
    }
    __syncthreads();

    // ---- per-row key min/max ----
    {
        unsigned kmn[RB], kmx[RB];
        #pragma unroll
        for (int r = 0; r < RB; ++r) { kmn[r] = 0xFFFFFFFFu; kmx[r] = 0u; }
        #pragma unroll
        for (int j = 0; j < 9; ++j) {
            int m = tid + j * 256;
            #pragma unroll
            for (int r = 0; r < RB; ++r) {
                unsigned k = fkey(rows[r][m]);
                kmn[r] = min(kmn[r], k); kmx[r] = max(kmx[r], k);
            }
        }
        #pragma unroll
        for (int r = 0; r < RB; ++r) {
            #pragma unroll
            for (int off = 32; off > 0; off >>= 1) {
                unsigned a = (unsigned)__shfl_down((int)kmn[r], off);
                unsigned b = (unsigned)__shfl_down((int)kmx[r], off);
                kmn[r] = min(kmn[r], a); kmx[r] = max(kmx[r], b);
            }
            if (lane == 0) { mred[wid][r][0] = kmn[r]; mred[wid][r][1] = kmx[r]; }
        }
        __syncthreads();
        if (tid < RB) {
            unsigned a = min(min(mred[0][tid][0], mred[1][tid][0]),
                             min(mred[2][tid][0], mred[3][tid][0]));
            unsigned b = max(max(mred[0][tid][1], mred[1][tid][1]),
                             max(mred[2][tid][1], mred[3][tid][1]));
            rowKmin[tid] = a; rowKmax[tid] = b;
        }
        __syncthreads();
    }

    // ---- exact select per row: threshold key + tie cut index ----
    for (int r = 0; r < RB; ++r) {
        unsigned klo = rowKmin[r], khi = rowKmax[r];
        unsigned remK = TOPK;
        unsigned cnt = NN;
        unsigned T = khi, tieTake = 1, eqCnt = 1;
        bool done = false;
        for (int iter = 0; iter < 8 && !done; ++iter) {
            if (cnt <= 64u) {
                if (tid == 0) sScnt = 0;
                __syncthreads();
                #pragma unroll
                for (int j = 0; j < 9; ++j) {
                    int m = tid + j * 256;
                    unsigned k = fkey(rows[r][m]);
                    if (k >= klo && k <= khi) {
                        unsigned idx = atomicAdd(&sScnt, 1u);
                        candk[idx] = k;
                    }
                }
                __syncthreads();
                if (wid == 0) {
                    unsigned myk = (lane < (int)cnt) ? candk[lane] : 0u;
                    unsigned gtr = 0, eq = 0;
                    for (int i = 0; i < (int)cnt; ++i) {
                        unsigned ki = candk[i];
                        gtr += (ki > myk) ? 1u : 0u;
                        eq  += (ki == myk) ? 1u : 0u;
                    }
                    if (lane < (int)cnt && gtr < remK && remK <= gtr + eq) {
                        sT = myk; sTie = remK - gtr; sEq = eq;
                    }
                }
                __syncthreads();
                T = sT; tieTake = sTie; eqCnt = sEq;
                done = true;
            } else if (klo == khi) {
                T = klo; tieTake = remK; eqCnt = cnt;
                done = true;
            } else {
                unsigned d = khi - klo;
                int shift = (d <= 255u) ? 0 : (24 - __clz(d));
                hist[tid] = 0;
                __syncthreads();
                #pragma unroll
                for (int j = 0; j < 9; ++j) {
                    int m = tid + j * 256;
                    unsigned k = fkey(rows[r][m]);
                    if (k >= klo && k <= khi)
                        atomicAdd(&hist[(k - klo) >> shift], 1u);
                }
                __syncthreads();
                unsigned c = hist[tid];
                unsigned s = c;
                #pragma unroll
                for (int off = 1; off < 64; off <<= 1) {
                    unsigned v = (unsigned)__shfl_down((int)s, off);
                    if (lane + off < 64) s += v;
                }
                if (lane == 0) wtot[wid] = s;
                __syncthreads();
                unsigned addw = 0;
                for (int w = wid + 1; w < 4; ++w) addw += wtot[w];
                s += addw;
                if (s >= remK && s - c < remK) { sBin = tid; sAbove = s - c; sCnt = c; }
                __syncthreads();
                unsigned b = sBin;
                remK -= sAbove;
                cnt = sCnt;
                unsigned nlo = klo + (b << shift);
                unsigned long long nhiL =
                    (unsigned long long)klo + (((unsigned long long)(b + 1)) << shift) - 1ull;
                unsigned nhi = (nhiL > (unsigned long long)khi) ? khi : (unsigned)nhiL;
                klo = nlo; khi = nhi;
            }
        }
        if (tieTake == eqCnt) {
            if (tid == 0) { cutIdx[r] = NN - 1; Tkey[r] = T; }
        } else {
            if (tid == 0) {
                unsigned need = tieTake, seen = 0; int cut = NN - 1;
                for (int m = 0; m < NN; ++m) {
                    if (fkey(rows[r][m]) == T) { if (++seen == need) { cut = m; break; } }
                }
                cutIdx[r] = cut; Tkey[r] = T;
            }
        }
        __syncthreads();
    }

    // ---- exp over selected, zero elsewhere; per-row sums ----
    {
        unsigned T0 = Tkey[0], T1 = Tkey[1], T2 = Tkey[2], T3 = Tkey[3];
        int c0 = cutIdx[0], c1 = cutIdx[1], c2 = cutIdx[2], c3 = cutIdx[3];
        float mx0 = fkey_inv(rowKmax[0]), mx1 = fkey_inv(rowKmax[1]);
        float mx2 = fkey_inv(rowKmax[2]), mx3 = fkey_inv(rowKmax[3]);
        float ls0 = 0.f, ls1 = 0.f, ls2 = 0.f, ls3 = 0.f;
        #pragma unroll
        for (int j = 0; j < 9; ++j) {
            int m = tid + j * 256;
            {
                float a = rows[0][m]; unsigned k = fkey(a);
                bool inc = (k > T0) || (k == T0 && m <= c0);
                float e = inc ? __expf(a - mx0) : 0.f; rows[0][m] = e; ls0 += e;
            }
            {
                float a = rows[1][m]; unsigned k = fkey(a);
                bool inc = (k > T1) || (k == T1 && m <= c1);
                float e = inc ? __expf(a - mx1) : 0.f; rows[1][m] = e; ls1 += e;
            }
            {
                float a = rows[2][m]; unsigned k = fkey(a);
                bool inc = (k > T2) || (k == T2 && m <= c2);
                float e = inc ? __expf(a - mx2) : 0.f; rows[2][m] = e; ls2 += e;
            }
            {
                float a = rows[3][m]; unsigned k = fkey(a);
                bool inc = (k > T3) || (k == T3 && m <= c3);
                float e = inc ? __expf(a - mx3) : 0.f; rows[3][m] = e; ls3 += e;
            }
        }
        #pragma unroll
        for (int off = 32; off > 0; off >>= 1) {
            ls0 += __shfl_down(ls0, off); ls1 += __shfl_down(ls1, off);
            ls2 += __shfl_down(ls2, off); ls3 += __shfl_down(ls3, off);
        }
        if (lane == 0) {
            fred[wid][0] = ls0; fred[wid][1] = ls1;
            fred[wid][2] = ls2; fred[wid][3] = ls3;
        }
        __syncthreads();
        if (tid < RB)
            rdenom[tid] = 1.f / (fred[0][tid] + fred[1][tid] + fred[2][tid] + fred[3][tid]);
        __syncthreads();
    }

    // ---- PV: wave `wid` owns channels [wid*8, wid*8+8); V loads shared by 4 rows
    {
        int cb = wid * 8;
        float acc[RB][8];
        #pragma unroll
        for (int r = 0; r < RB; ++r)
            #pragma unroll
            for (int cl = 0; cl < 8; ++cl) acc[r][cl] = 0.f;
        for (int j = 0; j < 36; ++j) {
            int m = lane + j * 64;
            float p0 = rows[0][m], p1 = rows[1][m], p2 = rows[2][m], p3 = rows[3][m];
            #pragma unroll
            for (int cl = 0; cl < 8; ++cl) {
                float v = Vb[(size_t)(cb + cl) * NN + m];
                acc[0][cl] += p0 * v; acc[1][cl] += p1 * v;
                acc[2][cl] += p2 * v; acc[3][cl] += p3 * v;
            }
        }
        #pragma unroll
        for (int r = 0; r < RB; ++r)
            #pragma unroll
            for (int cl = 0; cl < 8; ++cl) {
                float v = acc[r][cl];
                #pragma unroll
                for (int off = 32; off > 0; off >>= 1) v += __shfl_down(v, off);
                acc[r][cl] = v;
            }
        if (lane == 0) {
            #pragma unroll
            for (int r = 0; r < RB; ++r) {
                float rinv = rdenom[r];
                #pragma unroll
                for (int cl = 0; cl < 8; ++cl) {
                    int cfull = r * CS + h * CHD + cb + cl;   // n = g*4+r -> t=r, p=g
                    aout[(size_t)cfull * HW + g] = acc[r][cl] * rinv;
                }
            }
        }
    }
}

// ---------------------------------------------------------------------------
// Kernel 4: out = x + w_proj @ aout   (M=1024, N=576, K=1024)
// ---------------------------------------------------------------------------
#define BM 64
#define BN 64
#define BK 16
__global__ __launch_bounds__(256) void proj_kernel(
    const float* __restrict__ aout, const float* __restrict__ wproj,
    const float* __restrict__ x, float* __restrict__ out)
{
    __shared__ float As[BM][BK + 1];
    __shared__ float Bs[BK][BN + 1];
    int bx = blockIdx.x;   // p tiles: 0..8
    int by = blockIdx.y;   // o tiles: 0..15
    int tid = threadIdx.x;
    int tx = tid & 15, ty = tid >> 4;
    float acc[4][4] = {{0.f}};
    for (int kt = 0; kt < DIM; kt += BK) {
        #pragma unroll
        for (int i = 0; i < 4; ++i) {
            int idx = tid + i * 256;
            int r = idx >> 4, cc = idx & 15;
            As[r][cc] = wproj[(size_t)(by * BM + r) * DIM + kt + cc];
        }
        #pragma unroll
        for (int i = 0; i < 4; ++i) {
            int idx = tid + i * 256;
            int r = idx >> 6, p = idx & 63;
            Bs[r][p] = aout[(size_t)(kt + r) * HW + bx * BN + p];
        }
        __syncthreads();
        #pragma unroll
        for (int kk = 0; kk < BK; ++kk) {
            float a[4], b[4];
            #pragma unroll
            for (int i = 0; i < 4; ++i) a[i] = As[ty * 4 + i][kk];
            #pragma unroll
            for (int j = 0; j < 4; ++j) b[j] = Bs[kk][tx * 4 + j];
            #pragma unroll
            for (int i = 0; i < 4; ++i)
                #pragma unroll
                for (int j = 0; j < 4; ++j) acc[i][j] += a[i] * b[j];
        }
        __syncthreads();
    }
    #pragma unroll
    for (int i = 0; i < 4; ++i) {
        int o = by * BM + ty * 4 + i;
        #pragma unroll
        for (int j = 0; j < 4; ++j) {
            int p = bx * BN + tx * 4 + j;
            out[(size_t)o * HW + p] = x[(size_t)o * HW + p] + acc[i][j];
        }
    }
}

// ---------------------------------------------------------------------------
extern "C" void kernel_launch(void* const* d_in, const int* in_sizes, int n_in,
                              void* d_out, int out_size, void* d_ws, size_t ws_size,
                              hipStream_t stream)
{
    const float* x     = (const float*)d_in[0];
    const float* temp  = (const float*)d_in[1];
    const float* w_qkv = (const float*)d_in[2];
    const float* w_dw  = (const float*)d_in[3];
    const float* wproj = (const float*)d_in[4];
    float* out = (float*)d_out;

    const size_t TSZ = (size_t)NHEADS * CHD * NN;   // 589824 floats
    float* ws = (float*)d_ws;
    float* qb   = ws;
    float* kb   = ws + TSZ;
    float* vb   = ws + 2 * TSZ;
    float* aout = ws + 3 * TSZ;

    qkv_conv_kernel<<<256, 256, 0, stream>>>(x, w_qkv, w_dw, qb, kb, vb);
    normalize_kernel<<<512, 256, 0, stream>>>(qb, kb);
    attn_rows_kernel<<<NHEADS * HW, 256, 0, stream>>>(qb, kb, vb, temp, aout);
    proj_kernel<<<dim3(9, 16), 256, 0, stream>>>(aout, wproj, x, out);
}